// Round 2
// baseline (8936.736 us; speedup 1.0000x reference)
//
#include <hip/hip_runtime.h>
#include <hip/hip_bf16.h>

// Problem constants (S,B,D,H,T) = (4,512,256,1024,50)
#define S_ 4
#define B_ 512
#define D_ 256
#define H_ 1024
#define T_ 50
#define M_ (S_*B_)   // 2048 rows total

typedef __attribute__((ext_vector_type(8))) __bf16 bf16x8;
typedef __attribute__((ext_vector_type(4))) float  f32x4;

__device__ __forceinline__ void gld16(const void* g, void* l) {
  // async global->LDS, 16B per lane. LDS dest must be wave-uniform base + lane*16.
  __builtin_amdgcn_global_load_lds(
      (const __attribute__((address_space(1))) void*)g,
      (__attribute__((address_space(3))) void*)l, 16, 0, 0);
}

// NaN-free fast tanh: saturates to +/-1, ~1e-6 abs error (<< bf16 eps)
__device__ __forceinline__ float fast_tanh(float x) {
  const float e = __expf(2.f * x);
  return 1.f - 2.f / (e + 1.f);
}

// ---------------------------------------------------------------------------
// Runtime dtype detection + dt table.
//   flags[0] = weights/first_point/output are f32 (1) or bf16 (0)
//   flags[1] = time grid is f32 (1) or bf16 (0)
// Discriminators:
//   time grid: first 32-bit word is bits of 0.0f (==0) iff f32 linspace.
//   weights:  W2 ~ N(0,1/32). Sample 256 u16s; bf16 values essentially never
//             have |x|>=2 (exp field >=128); f32 low halves are uniform bits
//             -> ~50% do.
// ---------------------------------------------------------------------------
__global__ void detect_k(const void* t_raw, const void* w2_raw,
                         float* dts, int* flags) {
  __shared__ int cnt;
  const int l = threadIdx.x;           // 64 threads, 1 block
  if (l == 0) cnt = 0;
  __syncthreads();
  const unsigned short* u = (const unsigned short*)w2_raw;
  int c = 0;
  #pragma unroll
  for (int j = 0; j < 4; ++j) {
    const unsigned short v = u[l * 4 + j];
    const unsigned e = (v >> 7) & 0xFF;          // bf16 exponent field
    if (e >= 128) c++;                            // |x| >= 2.0 or NaN/Inf
  }
  atomicAdd(&cnt, c);
  __syncthreads();
  const unsigned tw0 = *(const unsigned*)t_raw;
  const int t_is_f32 = (tw0 == 0u) ? 1 : 0;
  const int w_is_f32 = (cnt > 16) ? 1 : 0;
  if (l == 0) { flags[0] = w_is_f32; flags[1] = t_is_f32; }
  if (l < T_ - 1) {
    float t0, t1;
    if (t_is_f32) {
      const float* tf = (const float*)t_raw;
      t0 = tf[l]; t1 = tf[l + 1];
    } else {
      const __hip_bfloat16* tb = (const __hip_bfloat16*)t_raw;
      t0 = __bfloat162float(tb[l]); t1 = __bfloat162float(tb[l + 1]);
    }
    dts[l] = t1 - t0;
  }
}

// ---------------------------------------------------------------------------
// setup: y(fp32) = first_point; out[:, t=0] = first_point; reg_state = 0
// ---------------------------------------------------------------------------
__global__ void setup_k(const void* __restrict__ fp_raw,
                        float* __restrict__ y, void* __restrict__ out,
                        const int* __restrict__ flags) {
  const int i = blockIdx.x * 256 + threadIdx.x;   // over M_*D_
  const int f32 = flags[0];
  const float v = f32 ? ((const float*)fp_raw)[i]
                      : __bfloat162float(((const __hip_bfloat16*)fp_raw)[i]);
  y[i] = v;
  const int m = i >> 8, d = i & 255;              // D_=256
  const size_t o = (size_t)(m * T_) * D_ + d;
  if (f32) ((float*)out)[o] = v;
  else     ((__hip_bfloat16*)out)[o] = __float2bfloat16(v);
  if (i < S_) {
    const size_t ro = (size_t)M_ * T_ * D_ + i;
    if (f32) ((float*)out)[ro] = 0.f;
    else     ((__hip_bfloat16*)out)[ro] = __float2bfloat16(0.f);
  }
}

// ---------------------------------------------------------------------------
// transpose to bf16: dst[N][K] = bf16(src[K][N]); src dtype per flags[0]
// ---------------------------------------------------------------------------
__global__ void transpose_k(const void* __restrict__ src,
                            __hip_bfloat16* __restrict__ dst, int K, int N,
                            const int* __restrict__ flags) {
  __shared__ __hip_bfloat16 tile[32][33];
  const int f32 = flags[0];
  const int tx = threadIdx.x, ty = threadIdx.y;
  const int nb = blockIdx.x * 32, kb = blockIdx.y * 32;
  #pragma unroll
  for (int j = 0; j < 32; j += 8) {
    const size_t si = (size_t)(kb + ty + j) * N + nb + tx;
    tile[ty + j][tx] = f32 ? __float2bfloat16(((const float*)src)[si])
                           : ((const __hip_bfloat16*)src)[si];
  }
  __syncthreads();
  #pragma unroll
  for (int j = 0; j < 32; j += 8)
    dst[(size_t)(nb + ty + j) * K + kb + tx] = tile[tx][ty + j];
}

// ---------------------------------------------------------------------------
// biases -> fp32 workspace arrays
// ---------------------------------------------------------------------------
__global__ void prep_bias_k(const void* b1r, const void* b2r, const void* b3r,
                            float* bf1, float* bf2, float* bf3,
                            const int* flags) {
  const int i = blockIdx.x * 256 + threadIdx.x;   // H_ threads
  const int f32 = flags[0];
  bf1[i] = f32 ? ((const float*)b1r)[i]
               : __bfloat162float(((const __hip_bfloat16*)b1r)[i]);
  bf2[i] = f32 ? ((const float*)b2r)[i]
               : __bfloat162float(((const __hip_bfloat16*)b2r)[i]);
  if (i < D_)
    bf3[i] = f32 ? ((const float*)b3r)[i]
                 : __bfloat162float(((const __hip_bfloat16*)b3r)[i]);
}

// ---------------------------------------------------------------------------
// Unified MFMA GEMM.  C[M,N] = A[M,K] @ Bt[N,K]^T  (Bt pre-transposed weights)
//   AFROM: 0 = A is bf16 array, staged via global_load_lds
//          1 = A built on the fly: u = y + ccoef*dt*k_prev  (fp32 inputs)
//   EPI:   0 = h_out = bf16(tanh(acc + bias))
//          1 = kv = acc+bias; kout = kv; accb = wacc*kv (+ accb if !isFirst)
//          2 = kv = acc+bias; y += dt/6*(accb+kv); traj[t+1] = y (out dtype)
// ---------------------------------------------------------------------------
template <int BM, int BN, int KDIM, int AFROM, int EPI>
__global__ __launch_bounds__(256, 2) void gemm_k(
    const __hip_bfloat16* __restrict__ A,
    const float* __restrict__ Ay, const float* __restrict__ Akk,
    const __hip_bfloat16* __restrict__ Bt,
    const float* __restrict__ bias,
    __hip_bfloat16* __restrict__ Cbf, int ldc,
    float* __restrict__ kout, float* __restrict__ accb,
    float* __restrict__ yio, void* __restrict__ traj,
    const float* __restrict__ dts, const int* __restrict__ flags, int tstep,
    float ccoef, float wacc, int isFirst) {
  constexpr int TM = BM / 2, TN = BN / 2;
  constexpr int NMI = TM / 16, NNI = TN / 16;
  const int tid = threadIdx.x;
  const int wave = tid >> 6, lane = tid & 63;
  const int quad = lane >> 4, l16 = lane & 15;
  const int m0 = blockIdx.x * BM, n0 = blockIdx.y * BN;
  const int wm0 = (wave & 1) * TM, wn0 = (wave >> 1) * TN;

  __shared__ __hip_bfloat16 lA[BM * 32];
  __shared__ __hip_bfloat16 lB[BN * 32];

  f32x4 acc[NMI][NNI];
  #pragma unroll
  for (int i = 0; i < NMI; i++)
    #pragma unroll
    for (int j = 0; j < NNI; j++) acc[i][j] = f32x4{0.f, 0.f, 0.f, 0.f};

  float dtv = 0.f;
  if (AFROM == 1 || EPI == 2) dtv = dts[tstep];
  const float cdt = ccoef * dtv;
  int ofl = 0;
  if (EPI == 2) ofl = flags[0];

  for (int k0 = 0; k0 < KDIM; k0 += 32) {
    // ---- stage A tile [BM x 32] ----
    if (AFROM == 0) {
      #pragma unroll
      for (int inst = 0; inst < (BM * 32) / 2048; ++inst) {
        const int e = (inst * 256 + tid) * 8;           // 8 bf16 = 16B / lane
        gld16(&A[(size_t)(m0 + (e >> 5)) * KDIM + k0 + (e & 31)], &lA[e]);
      }
    } else {
      #pragma unroll
      for (int inst = 0; inst < (BM * 32) / 1024; ++inst) {
        const int e = (inst * 256 + tid) * 4;           // 4 elems / thread
        const int r = e >> 5, c = e & 31;
        const float4 yv = *(const float4*)&Ay [(size_t)(m0 + r) * KDIM + k0 + c];
        const float4 kv = *(const float4*)&Akk[(size_t)(m0 + r) * KDIM + k0 + c];
        ushort4 pk;
        pk.x = __builtin_bit_cast(unsigned short, __float2bfloat16(yv.x + cdt * kv.x));
        pk.y = __builtin_bit_cast(unsigned short, __float2bfloat16(yv.y + cdt * kv.y));
        pk.z = __builtin_bit_cast(unsigned short, __float2bfloat16(yv.z + cdt * kv.z));
        pk.w = __builtin_bit_cast(unsigned short, __float2bfloat16(yv.w + cdt * kv.w));
        *(ushort4*)&lA[e] = pk;
      }
    }
    // ---- stage B tile [BN x 32] (pre-transposed weights) ----
    #pragma unroll
    for (int inst = 0; inst < (BN * 32) / 2048; ++inst) {
      const int e = (inst * 256 + tid) * 8;
      gld16(&Bt[(size_t)(n0 + (e >> 5)) * KDIM + k0 + (e & 31)], &lB[e]);
    }
    __syncthreads();
    // ---- MFMA ----
    bf16x8 aF[NMI], bF[NNI];
    #pragma unroll
    for (int mi = 0; mi < NMI; mi++)
      aF[mi] = *(const bf16x8*)&lA[(wm0 + mi * 16 + l16) * 32 + quad * 8];
    #pragma unroll
    for (int ni = 0; ni < NNI; ni++)
      bF[ni] = *(const bf16x8*)&lB[(wn0 + ni * 16 + l16) * 32 + quad * 8];
    #pragma unroll
    for (int mi = 0; mi < NMI; mi++)
      #pragma unroll
      for (int ni = 0; ni < NNI; ni++)
        acc[mi][ni] = __builtin_amdgcn_mfma_f32_16x16x32_bf16(
            aF[mi], bF[ni], acc[mi][ni], 0, 0, 0);
    __syncthreads();
  }

  // ---- epilogue ----  C/D layout: col = lane&15, row = quad*4 + reg
  #pragma unroll
  for (int mi = 0; mi < NMI; mi++) {
    #pragma unroll
    for (int ni = 0; ni < NNI; ni++) {
      const int gn = n0 + wn0 + ni * 16 + l16;
      const float bv = bias[gn];
      #pragma unroll
      for (int r = 0; r < 4; r++) {
        const int gm = m0 + wm0 + mi * 16 + quad * 4 + r;
        const float v = acc[mi][ni][r] + bv;
        if (EPI == 0) {
          Cbf[(size_t)gm * ldc + gn] = __float2bfloat16(fast_tanh(v));
        } else if (EPI == 1) {
          const int idx = gm * D_ + gn;
          kout[idx] = v;
          float a = wacc * v;
          if (!isFirst) a += accb[idx];
          accb[idx] = a;
        } else {
          const int idx = gm * D_ + gn;
          const float yv = yio[idx] + (dtv * (1.f / 6.f)) * (accb[idx] + v);
          yio[idx] = yv;
          const size_t off = (size_t)(gm * T_ + (tstep + 1)) * D_ + gn;
          if (ofl) ((float*)traj)[off] = yv;
          else     ((__hip_bfloat16*)traj)[off] = __float2bfloat16(yv);
        }
      }
    }
  }
}

// ---------------------------------------------------------------------------
extern "C" void kernel_launch(void* const* d_in, const int* in_sizes, int n_in,
                              void* d_out, int out_size, void* d_ws, size_t ws_size,
                              hipStream_t stream) {
  const void* fp   = d_in[0];
  const void* tarr = d_in[1];
  const void* W1   = d_in[2];
  const void* b1   = d_in[3];
  const void* W2   = d_in[4];
  const void* b2   = d_in[5];
  const void* W3   = d_in[6];
  const void* b3   = d_in[7];

  // workspace carve (~17 MB total)
  char* ws = (char*)d_ws;
  float* y    = (float*)ws;                  ws += (size_t)M_ * D_ * 4;
  float* kbuf = (float*)ws;                  ws += (size_t)M_ * D_ * 4;
  float* accb = (float*)ws;                  ws += (size_t)M_ * D_ * 4;
  float* bf1  = (float*)ws;                  ws += (size_t)H_ * 4;
  float* bf2  = (float*)ws;                  ws += (size_t)H_ * 4;
  float* bf3  = (float*)ws;                  ws += (size_t)D_ * 4;
  float* dts  = (float*)ws;                  ws += 64 * 4;
  int*   flags= (int*)ws;                    ws += 64 * 4;
  __hip_bfloat16* h1  = (__hip_bfloat16*)ws; ws += (size_t)M_ * H_ * 2;
  __hip_bfloat16* h2  = (__hip_bfloat16*)ws; ws += (size_t)M_ * H_ * 2;
  __hip_bfloat16* W1t = (__hip_bfloat16*)ws; ws += (size_t)H_ * D_ * 2;
  __hip_bfloat16* W2t = (__hip_bfloat16*)ws; ws += (size_t)H_ * H_ * 2;
  __hip_bfloat16* W3t = (__hip_bfloat16*)ws; ws += (size_t)D_ * H_ * 2;

  detect_k<<<1, 64, 0, stream>>>(tarr, W2, dts, flags);
  setup_k<<<(M_ * D_) / 256, 256, 0, stream>>>(fp, y, d_out, flags);
  dim3 tb(32, 8);
  transpose_k<<<dim3(H_ / 32, D_ / 32), tb, 0, stream>>>(W1, W1t, D_, H_, flags);
  transpose_k<<<dim3(H_ / 32, H_ / 32), tb, 0, stream>>>(W2, W2t, H_, H_, flags);
  transpose_k<<<dim3(D_ / 32, H_ / 32), tb, 0, stream>>>(W3, W3t, H_, D_, flags);
  prep_bias_k<<<H_ / 256, 256, 0, stream>>>(b1, b2, b3, bf1, bf2, bf3, flags);

  for (int st = 0; st < T_ - 1; ++st) {
    for (int stage = 0; stage < 4; ++stage) {
      const float cc = (stage == 0) ? 0.f : (stage == 3 ? 1.f : 0.5f);
      const float w  = (stage == 1 || stage == 2) ? 2.f : 1.f;
      // L1: u = y + cc*dt*k_prev ; h1 = tanh(u @ W1 + b1)
      gemm_k<128, 64, D_, 1, 0><<<dim3(M_ / 128, H_ / 64), 256, 0, stream>>>(
          nullptr, y, kbuf, W1t, bf1, h1, H_,
          nullptr, nullptr, nullptr, nullptr, dts, flags, st, cc, 0.f, 0);
      // L2: h2 = tanh(h1 @ W2 + b2)
      gemm_k<128, 64, H_, 0, 0><<<dim3(M_ / 128, H_ / 64), 256, 0, stream>>>(
          h1, nullptr, nullptr, W2t, bf2, h2, H_,
          nullptr, nullptr, nullptr, nullptr, dts, flags, st, 0.f, 0.f, 0);
      // L3: k = h2 @ W3 + b3 ; RK4 bookkeeping fused in epilogue
      if (stage < 3) {
        gemm_k<64, 64, H_, 0, 1><<<dim3(M_ / 64, D_ / 64), 256, 0, stream>>>(
            h2, nullptr, nullptr, W3t, bf3, nullptr, D_,
            kbuf, accb, nullptr, nullptr, dts, flags, st, 0.f, w, stage == 0 ? 1 : 0);
      } else {
        gemm_k<64, 64, H_, 0, 2><<<dim3(M_ / 64, D_ / 64), 256, 0, stream>>>(
            h2, nullptr, nullptr, W3t, bf3, nullptr, D_,
            nullptr, accb, y, d_out, dts, flags, st, 0.f, 0.f, 0);
      }
    }
  }
}